// Round 10
// baseline (266.231 us; speedup 1.0000x reference)
//
#include <hip/hip_runtime.h>
#include <math.h>

#define N_NODES 50000
#define N_EDGES 800000
#define N_GRAPHS 64
#define NEG_SLOPE 0.2f
#define SCAN_BS 512
#define SCAN_NB ((N_NODES + SCAN_BS - 1) / SCAN_BS)   // 98

typedef __attribute__((ext_vector_type(8))) short short8;
typedef __attribute__((ext_vector_type(4))) float f32x4;

__device__ __forceinline__ float lrelu(float x) { return x > 0.f ? x : NEG_SLOPE * x; }

__device__ __forceinline__ unsigned short f2bf(float f) {
    union { float f; unsigned int u; } v; v.f = f;
    unsigned int r = (v.u + 0x7fffu + ((v.u >> 16) & 1u)) >> 16;  // RNE
    return (unsigned short)r;
}
__device__ __forceinline__ float bf2f(unsigned short b) {
    union { unsigned int u; float f; } v; v.u = ((unsigned int)b) << 16;
    return v.f;
}

__device__ __forceinline__ int lower_bound_i(const int* __restrict__ a, int n, int v) {
    int lo = 0, hi = n;
    while (lo < hi) { int m = (lo + hi) >> 1; if (a[m] < v) lo = m + 1; else hi = m; }
    return lo;
}

// ---------------- CSR build ----------------
__global__ void k_count(const int* __restrict__ dst, int* __restrict__ cnt) {
    int e = blockIdx.x * blockDim.x + threadIdx.x;
    if (e < N_EDGES) atomicAdd(&cnt[dst[e]], 1);
}

__global__ __launch_bounds__(SCAN_BS) void k_scan1(const int* __restrict__ cnt,
                                                   int* __restrict__ local_pref,
                                                   int* __restrict__ blk_sum) {
    const int t = threadIdx.x;
    const int gid = blockIdx.x * SCAN_BS + t;
    const int lane = t & 63, w = t >> 6;
    int v = (gid < N_NODES) ? cnt[gid] : 0;
    int x = v;
#pragma unroll
    for (int off = 1; off < 64; off <<= 1) {
        int y = __shfl_up(x, off, 64);
        if (lane >= off) x += y;
    }
    __shared__ int wsum[SCAN_BS / 64];
    __shared__ int wpre[SCAN_BS / 64];
    if (lane == 63) wsum[w] = x;
    __syncthreads();
    if (t == 0) {
        int run = 0;
#pragma unroll
        for (int i = 0; i < SCAN_BS / 64; ++i) { wpre[i] = run; run += wsum[i]; }
    }
    __syncthreads();
    int excl = x - v + wpre[w];
    if (gid < N_NODES) local_pref[gid] = excl;
    if (t == SCAN_BS - 1) blk_sum[blockIdx.x] = excl + v;
}

__global__ __launch_bounds__(128) void k_scan2(const int* __restrict__ blk_sum,
                                               int* __restrict__ blk_base,
                                               int* __restrict__ row_start) {
    const int t = threadIdx.x;
    const int lane = t & 63;
    int v = (t < SCAN_NB) ? blk_sum[t] : 0;
    int x = v;
#pragma unroll
    for (int off = 1; off < 64; off <<= 1) {
        int y = __shfl_up(x, off, 64);
        if (lane >= off) x += y;
    }
    __shared__ int wsum0;
    if (t == 63) wsum0 = x;
    __syncthreads();
    int excl = x - v + ((t >= 64) ? wsum0 : 0);
    if (t < SCAN_NB) blk_base[t] = excl;
    if (t == 127) row_start[N_NODES] = excl + v;  // grand total
}

__global__ __launch_bounds__(SCAN_BS) void k_scan3(const int* __restrict__ local_pref,
                                                   const int* __restrict__ blk_base,
                                                   int* __restrict__ row_start,
                                                   int* __restrict__ cursor) {
    const int gid = blockIdx.x * SCAN_BS + threadIdx.x;
    if (gid < N_NODES) {
        int r = local_pref[gid] + blk_base[blockIdx.x];
        row_start[gid] = r;
        cursor[gid] = r;
    }
}

__global__ void k_fill(const int* __restrict__ src, const int* __restrict__ dst,
                       int* __restrict__ cursor, int* __restrict__ csr_src) {
    int e = blockIdx.x * blockDim.x + threadIdx.x;
    if (e < N_EDGES) {
        int d = dst[e];
        int p = atomicAdd(&cursor[d], 1);
        csr_src[p] = src[e];
    }
}

// ---------------- Layer 1 logits: a_s/a_d per node (h1 NOT materialized) -----
__global__ __launch_bounds__(256) void k_gemm1(const float* __restrict__ x,
                                               const float* __restrict__ W1,
                                               const float* __restrict__ att_s,
                                               const float* __restrict__ att_d,
                                               float4* __restrict__ a_s,
                                               float4* __restrict__ a_d) {
    __shared__ float Ws[5 * 256];
    const int t = threadIdx.x;
    for (int i = t; i < 5 * 256; i += 256) Ws[i] = W1[i];
    __syncthreads();
    const int wave = t >> 6, lane = t & 63;
    const int n = blockIdx.x * 4 + wave;
    if (n >= N_NODES) return;
    float x0 = x[n * 5 + 0], x1 = x[n * 5 + 1], x2 = x[n * 5 + 2],
          x3 = x[n * 5 + 3], x4 = x[n * 5 + 4];
    float vs[4], vd[4];
#pragma unroll
    for (int hd = 0; hd < 4; ++hd) {
        const int c = hd * 64 + lane;
        float h = x0 * Ws[c] + x1 * Ws[256 + c] + x2 * Ws[512 + c] +
                  x3 * Ws[768 + c] + x4 * Ws[1024 + c];
        vs[hd] = h * att_s[c];
        vd[hd] = h * att_d[c];
    }
#pragma unroll
    for (int off = 32; off; off >>= 1) {
#pragma unroll
        for (int hd = 0; hd < 4; ++hd) {
            vs[hd] += __shfl_xor(vs[hd], off, 64);
            vd[hd] += __shfl_xor(vd[hd], off, 64);
        }
    }
    if (lane == 0) {
        a_s[n] = make_float4(vs[0], vs[1], vs[2], vs[3]);
        a_d[n] = make_float4(vd[0], vd[1], vd[2], vd[3]);
    }
}

// ---------------- Layer 1 aggregation: SUM-SWAPPED ----------------
__global__ __launch_bounds__(256) void k_agg1(const float* __restrict__ x,
                                              const float* __restrict__ W1,
                                              const float4* __restrict__ asv,
                                              const float4* __restrict__ adv,
                                              const int* __restrict__ row_start,
                                              const int* __restrict__ csr_src,
                                              const float* __restrict__ b1,
                                              unsigned short* __restrict__ out1rm) {
    __shared__ float hand[4][4][24];   // [wave][grp][4 den + 20 Xw]
    const int t = threadIdx.x;
    const int wave = t >> 6, lane = t & 63;
    const int grp = lane >> 4, l16 = lane & 15;
    const int d = blockIdx.x * 16 + wave * 4 + grp;   // exact cover

    float w1r[4][5], bias[4];
#pragma unroll
    for (int h = 0; h < 4; ++h) {
#pragma unroll
        for (int i = 0; i < 5; ++i) w1r[h][i] = W1[i * 256 + h * 64 + lane];
        bias[h] = b1[h * 64 + lane];
    }

    const int beg = row_start[d], end = row_start[d + 1];
    const float4 ad = adv[d];

    float den[4] = {0.f, 0.f, 0.f, 0.f};
    float xw[4][5];
#pragma unroll
    for (int h = 0; h < 4; ++h)
#pragma unroll
        for (int i = 0; i < 5; ++i) xw[h][i] = 0.f;

    for (int cb = beg; cb < end; cb += 16) {
        const int j = cb + l16;
        if (j < end) {
            const int s = csr_src[j];
            const float4 a = asv[s];
            float w[4];
            w[0] = __expf(lrelu(a.x + ad.x));
            w[1] = __expf(lrelu(a.y + ad.y));
            w[2] = __expf(lrelu(a.z + ad.z));
            w[3] = __expf(lrelu(a.w + ad.w));
            const float* xp = x + (size_t)s * 5;
            float xv[5];
#pragma unroll
            for (int i = 0; i < 5; ++i) xv[i] = xp[i];
#pragma unroll
            for (int h = 0; h < 4; ++h) {
                den[h] += w[h];
#pragma unroll
                for (int i = 0; i < 5; ++i) xw[h][i] += w[h] * xv[i];
            }
        }
    }

#pragma unroll
    for (int off = 1; off < 16; off <<= 1) {
#pragma unroll
        for (int h = 0; h < 4; ++h) {
            den[h] += __shfl_xor(den[h], off, 64);
#pragma unroll
            for (int i = 0; i < 5; ++i) xw[h][i] += __shfl_xor(xw[h][i], off, 64);
        }
    }

    {   // self loop
        const float4 as = asv[d];
        float w[4];
        w[0] = __expf(lrelu(as.x + ad.x));
        w[1] = __expf(lrelu(as.y + ad.y));
        w[2] = __expf(lrelu(as.z + ad.z));
        w[3] = __expf(lrelu(as.w + ad.w));
        const float* xp = x + (size_t)d * 5;
        float xv[5];
#pragma unroll
        for (int i = 0; i < 5; ++i) xv[i] = xp[i];
#pragma unroll
        for (int h = 0; h < 4; ++h) {
            den[h] += w[h];
#pragma unroll
            for (int i = 0; i < 5; ++i) xw[h][i] += w[h] * xv[i];
        }
    }

    if (l16 == 0) {
#pragma unroll
        for (int h = 0; h < 4; ++h) hand[wave][grp][h] = den[h];
#pragma unroll
        for (int h = 0; h < 4; ++h)
#pragma unroll
            for (int i = 0; i < 5; ++i) hand[wave][grp][4 + h * 5 + i] = xw[h][i];
    }
    __syncthreads();

#pragma unroll
    for (int n = 0; n < 4; ++n) {
        const int dn = blockIdx.x * 16 + wave * 4 + n;
        unsigned short* op = out1rm + (size_t)dn * 256;
#pragma unroll
        for (int h = 0; h < 4; ++h) {
            const float dh = hand[wave][n][h] + 1e-16f;
            float hh = hand[wave][n][4 + h * 5 + 0] * w1r[h][0]
                     + hand[wave][n][4 + h * 5 + 1] * w1r[h][1]
                     + hand[wave][n][4 + h * 5 + 2] * w1r[h][2]
                     + hand[wave][n][4 + h * 5 + 3] * w1r[h][3]
                     + hand[wave][n][4 + h * 5 + 4] * w1r[h][4];
            op[h * 64 + lane] = f2bf(fmaxf(hh / dh + bias[h], 0.f));
        }
    }
}

// ---------------- Layer 2: MFMA GEMM (50000x256 @ 256x64) + attention logits ----
__global__ __launch_bounds__(256) void k_gemm2(const unsigned short* __restrict__ in,
                                               const float* __restrict__ W2,
                                               const float* __restrict__ att_s2,
                                               const float* __restrict__ att_d2,
                                               unsigned short* __restrict__ h2b,
                                               float* __restrict__ a_s2,
                                               float* __restrict__ a_d2) {
    __shared__ unsigned short lW[16384];  // 32 KB: [s][g][t][c16][j]
    const int t = threadIdx.x;
    for (int idx = t; idx < 16384; idx += 256) {
        int j = idx & 7, c16 = (idx >> 3) & 15, tt = (idx >> 7) & 3,
            g = (idx >> 9) & 3, s = idx >> 11;
        int k = 32 * s + 8 * g + j, c = 16 * tt + c16;
        lW[idx] = f2bf(W2[k * 64 + c]);
    }
    __syncthreads();
    const int wave = t >> 6, lane = t & 63;
    const int g = lane >> 4, c16 = lane & 15;
    const int nb = blockIdx.x * 64 + wave * 16;
    if (nb >= N_NODES) return;

    f32x4 acc[4];
#pragma unroll
    for (int i = 0; i < 4; ++i) acc[i] = (f32x4){0.f, 0.f, 0.f, 0.f};

    const unsigned short* arow = in + (size_t)(nb + c16) * 256;  // A row = lane&15
#pragma unroll
    for (int s = 0; s < 8; ++s) {
        short8 a = *reinterpret_cast<const short8*>(arow + 32 * s + 8 * g);
#pragma unroll
        for (int tt = 0; tt < 4; ++tt) {
            short8 b = *reinterpret_cast<const short8*>(
                lW + ((((s * 4 + g) * 4 + tt) * 16 + c16) << 3));
            acc[tt] = __builtin_amdgcn_mfma_f32_16x16x32_bf16(a, b, acc[tt], 0, 0, 0);
        }
    }

    float attS[4], attD[4];
#pragma unroll
    for (int tt = 0; tt < 4; ++tt) {
        attS[tt] = att_s2[16 * tt + c16];
        attD[tt] = att_d2[16 * tt + c16];
    }
#pragma unroll
    for (int r = 0; r < 4; ++r) {
        const int node = nb + g * 4 + r;
        const bool ok = node < N_NODES;
        float vs = 0.f, vd = 0.f;
#pragma unroll
        for (int tt = 0; tt < 4; ++tt) {
            float v = acc[tt][r];
            if (ok) h2b[(size_t)node * 64 + 16 * tt + c16] = f2bf(v);
            vs += v * attS[tt];
            vd += v * attD[tt];
        }
#pragma unroll
        for (int off = 1; off < 16; off <<= 1) {
            vs += __shfl_xor(vs, off, 64);
            vd += __shfl_xor(vd, off, 64);
        }
        if (ok && c16 == 0) { a_s2[node] = vs; a_d2[node] = vd; }
    }
}

// ---------------- Layer 2 aggregation + fused mean-pool accumulation ---------
__global__ __launch_bounds__(256) void k_agg2(const unsigned short* __restrict__ h2b,
                                              const float* __restrict__ as_,
                                              const float* __restrict__ ad_,
                                              const int* __restrict__ row_start,
                                              const int* __restrict__ csr_src,
                                              const float* __restrict__ b2,
                                              const int* __restrict__ batch,
                                              float* __restrict__ sums) {
    const int wave = threadIdx.x >> 6, lane = threadIdx.x & 63;
    const int d = blockIdx.x * 4 + wave;
    if (d >= N_NODES) return;
    const int beg = row_start[d], end = row_start[d + 1];
    const float adl = ad_[d];

    float den, acc;
    {
        float w = __expf(lrelu(as_[d] + adl));
        den = (lane == 0) ? w : 0.f;
        acc = w * bf2f(h2b[(size_t)d * 64 + lane]);
    }
    for (int c = beg; c < end; c += 64) {
        int rem = end - c; if (rem > 64) rem = 64;
        int sreg = 0;
        float wr = 0.f;
        if (lane < rem) {
            sreg = csr_src[c + lane];
            wr = __expf(lrelu(as_[sreg] + adl));
            den += wr;
        }
        int e = 0;
        for (; e + 8 <= rem; e += 8) {
            int sq[8];
#pragma unroll
            for (int q = 0; q < 8; ++q) sq[q] = __shfl(sreg, e + q, 64);
            unsigned short vq[8];
#pragma unroll
            for (int q = 0; q < 8; ++q) vq[q] = h2b[(size_t)sq[q] * 64 + lane];
#pragma unroll
            for (int q = 0; q < 8; ++q) {
                acc += __shfl(wr, e + q, 64) * bf2f(vq[q]);
            }
        }
        for (; e < rem; ++e) {
            int s = __shfl(sreg, e, 64);
            acc += __shfl(wr, e, 64) * bf2f(h2b[(size_t)s * 64 + lane]);
        }
    }
#pragma unroll
    for (int off = 32; off; off >>= 1) den += __shfl_xor(den, off, 64);
    float val = fmaxf(acc / (den + 1e-16f) + b2[lane], 0.f);
    atomicAdd(&sums[batch[d] * 64 + lane], val);
}

// ---------------- Final: mean + 64->2 linear (1 block) ----------------
__global__ __launch_bounds__(128) void k_final(const float* __restrict__ sums,
                                               const int* __restrict__ batch,
                                               const float* __restrict__ linW,
                                               const float* __restrict__ linb,
                                               float* __restrict__ out) {
    const int t = threadIdx.x;
    const int g = t >> 1, j = t & 1;
    int beg = lower_bound_i(batch, N_NODES, g);
    int end = lower_bound_i(batch, N_NODES, g + 1);
    float inv = 1.0f / fmaxf((float)(end - beg), 1.0f);
    float acc = linb[j];
    const float* sr = sums + g * 64;
#pragma unroll 8
    for (int c = 0; c < 64; ++c) acc += sr[c] * inv * linW[c * 2 + j];
    out[g * 2 + j] = acc;
}

extern "C" void kernel_launch(void* const* d_in, const int* in_sizes, int n_in,
                              void* d_out, int out_size, void* d_ws, size_t ws_size,
                              hipStream_t stream) {
    const float* x    = (const float*)d_in[0];
    const int*   ei   = (const int*)d_in[1];
    const int*   bat  = (const int*)d_in[2];
    const float* W1   = (const float*)d_in[3];
    const float* as1  = (const float*)d_in[4];
    const float* ad1  = (const float*)d_in[5];
    const float* b1   = (const float*)d_in[6];
    const float* W2   = (const float*)d_in[7];
    const float* as2  = (const float*)d_in[8];
    const float* ad2  = (const float*)d_in[9];
    const float* b2   = (const float*)d_in[10];
    const float* linW = (const float*)d_in[11];
    const float* linb = (const float*)d_in[12];
    float* out = (float*)d_out;

    const int* src = ei;
    const int* dst = ei + N_EDGES;

    char* w = (char*)d_ws;
    unsigned short* out1rm = (unsigned short*)w; w += (size_t)N_NODES * 256 * 2;
    float4* a_s1 = (float4*)w; w += (size_t)N_NODES * 16;
    float4* a_d1 = (float4*)w; w += (size_t)N_NODES * 16;
    unsigned short* h2b = (unsigned short*)w; w += (size_t)N_NODES * 64 * 2;
    float* a_s2  = (float*)w; w += (size_t)N_NODES * 4;
    float* a_d2  = (float*)w; w += (size_t)N_NODES * 4;
    float* sums  = (float*)w; w += (size_t)N_GRAPHS * 64 * 4;
    int* counts    = (int*)w; w += (size_t)N_NODES * 4;
    int* row_start = (int*)w; w += (size_t)(N_NODES + 64) * 4;
    int* cursor    = (int*)w; w += (size_t)N_NODES * 4;
    int* csr_src   = (int*)w; w += (size_t)N_EDGES * 4;
    int* blk_sum   = (int*)w; w += 128 * 4;
    int* blk_base  = (int*)w; w += 128 * 4;

    // CSR build (multi-block scan)
    hipMemsetAsync(counts, 0, (size_t)N_NODES * 4, stream);
    hipMemsetAsync(sums, 0, (size_t)N_GRAPHS * 64 * 4, stream);
    k_count<<<(N_EDGES + 255) / 256, 256, 0, stream>>>(dst, counts);
    k_scan1<<<SCAN_NB, SCAN_BS, 0, stream>>>(counts, cursor, blk_sum);
    k_scan2<<<1, 128, 0, stream>>>(blk_sum, blk_base, row_start);
    k_scan3<<<SCAN_NB, SCAN_BS, 0, stream>>>(cursor, blk_base, row_start, cursor);
    k_fill<<<(N_EDGES + 255) / 256, 256, 0, stream>>>(src, dst, cursor, csr_src);

    // Layer 1
    k_gemm1<<<(N_NODES + 3) / 4, 256, 0, stream>>>(x, W1, as1, ad1, a_s1, a_d1);
    k_agg1<<<N_NODES / 16, 256, 0, stream>>>(x, W1, a_s1, a_d1, row_start, csr_src, b1, out1rm);
    // Layer 2 (MFMA)
    k_gemm2<<<(N_NODES + 63) / 64, 256, 0, stream>>>(out1rm, W2, as2, ad2, h2b, a_s2, a_d2);
    k_agg2<<<(N_NODES + 3) / 4, 256, 0, stream>>>(h2b, a_s2, a_d2, row_start, csr_src, b2,
                                                  bat, sums);
    // Mean + linear
    k_final<<<1, 128, 0, stream>>>(sums, bat, linW, linb, out);
}

// Round 11
// 226.675 us; speedup vs baseline: 1.1745x; 1.1745x over previous
//
#include <hip/hip_runtime.h>
#include <math.h>

#define N_NODES 50000
#define N_EDGES 800000
#define N_GRAPHS 64
#define NEG_SLOPE 0.2f
#define SCAN_BS 512
#define SCAN_NB ((N_NODES + SCAN_BS - 1) / SCAN_BS)   // 98
#define N_REP 64   // pooled-sum replicas (contention breaker)

typedef __attribute__((ext_vector_type(8))) short short8;
typedef __attribute__((ext_vector_type(4))) float f32x4;

__device__ __forceinline__ float lrelu(float x) { return x > 0.f ? x : NEG_SLOPE * x; }

__device__ __forceinline__ unsigned short f2bf(float f) {
    union { float f; unsigned int u; } v; v.f = f;
    unsigned int r = (v.u + 0x7fffu + ((v.u >> 16) & 1u)) >> 16;  // RNE
    return (unsigned short)r;
}
__device__ __forceinline__ float bf2f(unsigned short b) {
    union { unsigned int u; float f; } v; v.u = ((unsigned int)b) << 16;
    return v.f;
}

__device__ __forceinline__ int lower_bound_i(const int* __restrict__ a, int n, int v) {
    int lo = 0, hi = n;
    while (lo < hi) { int m = (lo + hi) >> 1; if (a[m] < v) lo = m + 1; else hi = m; }
    return lo;
}

// ---------------- CSR build ----------------
__global__ void k_count(const int* __restrict__ dst, int* __restrict__ cnt) {
    int e = blockIdx.x * blockDim.x + threadIdx.x;
    if (e < N_EDGES) atomicAdd(&cnt[dst[e]], 1);
}

__global__ __launch_bounds__(SCAN_BS) void k_scan1(const int* __restrict__ cnt,
                                                   int* __restrict__ local_pref,
                                                   int* __restrict__ blk_sum) {
    const int t = threadIdx.x;
    const int gid = blockIdx.x * SCAN_BS + t;
    const int lane = t & 63, w = t >> 6;
    int v = (gid < N_NODES) ? cnt[gid] : 0;
    int x = v;
#pragma unroll
    for (int off = 1; off < 64; off <<= 1) {
        int y = __shfl_up(x, off, 64);
        if (lane >= off) x += y;
    }
    __shared__ int wsum[SCAN_BS / 64];
    __shared__ int wpre[SCAN_BS / 64];
    if (lane == 63) wsum[w] = x;
    __syncthreads();
    if (t == 0) {
        int run = 0;
#pragma unroll
        for (int i = 0; i < SCAN_BS / 64; ++i) { wpre[i] = run; run += wsum[i]; }
    }
    __syncthreads();
    int excl = x - v + wpre[w];
    if (gid < N_NODES) local_pref[gid] = excl;
    if (t == SCAN_BS - 1) blk_sum[blockIdx.x] = excl + v;
}

__global__ __launch_bounds__(128) void k_scan2(const int* __restrict__ blk_sum,
                                               int* __restrict__ blk_base,
                                               int* __restrict__ row_start) {
    const int t = threadIdx.x;
    const int lane = t & 63;
    int v = (t < SCAN_NB) ? blk_sum[t] : 0;
    int x = v;
#pragma unroll
    for (int off = 1; off < 64; off <<= 1) {
        int y = __shfl_up(x, off, 64);
        if (lane >= off) x += y;
    }
    __shared__ int wsum0;
    if (t == 63) wsum0 = x;
    __syncthreads();
    int excl = x - v + ((t >= 64) ? wsum0 : 0);
    if (t < SCAN_NB) blk_base[t] = excl;
    if (t == 127) row_start[N_NODES] = excl + v;  // grand total
}

__global__ __launch_bounds__(SCAN_BS) void k_scan3(const int* __restrict__ local_pref,
                                                   const int* __restrict__ blk_base,
                                                   int* __restrict__ row_start,
                                                   int* __restrict__ cursor) {
    const int gid = blockIdx.x * SCAN_BS + threadIdx.x;
    if (gid < N_NODES) {
        int r = local_pref[gid] + blk_base[blockIdx.x];
        row_start[gid] = r;
        cursor[gid] = r;
    }
}

__global__ void k_fill(const int* __restrict__ src, const int* __restrict__ dst,
                       int* __restrict__ cursor, int* __restrict__ csr_src) {
    int e = blockIdx.x * blockDim.x + threadIdx.x;
    if (e < N_EDGES) {
        int d = dst[e];
        int p = atomicAdd(&cursor[d], 1);
        csr_src[p] = src[e];
    }
}

// ---------------- Layer 1 logits: a_s/a_d per node (h1 NOT materialized) -----
__global__ __launch_bounds__(256) void k_gemm1(const float* __restrict__ x,
                                               const float* __restrict__ W1,
                                               const float* __restrict__ att_s,
                                               const float* __restrict__ att_d,
                                               float4* __restrict__ a_s,
                                               float4* __restrict__ a_d) {
    __shared__ float Ws[5 * 256];
    const int t = threadIdx.x;
    for (int i = t; i < 5 * 256; i += 256) Ws[i] = W1[i];
    __syncthreads();
    const int wave = t >> 6, lane = t & 63;
    const int n = blockIdx.x * 4 + wave;
    if (n >= N_NODES) return;
    float x0 = x[n * 5 + 0], x1 = x[n * 5 + 1], x2 = x[n * 5 + 2],
          x3 = x[n * 5 + 3], x4 = x[n * 5 + 4];
    float vs[4], vd[4];
#pragma unroll
    for (int hd = 0; hd < 4; ++hd) {
        const int c = hd * 64 + lane;
        float h = x0 * Ws[c] + x1 * Ws[256 + c] + x2 * Ws[512 + c] +
                  x3 * Ws[768 + c] + x4 * Ws[1024 + c];
        vs[hd] = h * att_s[c];
        vd[hd] = h * att_d[c];
    }
#pragma unroll
    for (int off = 32; off; off >>= 1) {
#pragma unroll
        for (int hd = 0; hd < 4; ++hd) {
            vs[hd] += __shfl_xor(vs[hd], off, 64);
            vd[hd] += __shfl_xor(vd[hd], off, 64);
        }
    }
    if (lane == 0) {
        a_s[n] = make_float4(vs[0], vs[1], vs[2], vs[3]);
        a_d[n] = make_float4(vd[0], vd[1], vd[2], vd[3]);
    }
}

// ---------------- Layer 1 aggregation: SUM-SWAPPED ----------------
__global__ __launch_bounds__(256) void k_agg1(const float* __restrict__ x,
                                              const float* __restrict__ W1,
                                              const float4* __restrict__ asv,
                                              const float4* __restrict__ adv,
                                              const int* __restrict__ row_start,
                                              const int* __restrict__ csr_src,
                                              const float* __restrict__ b1,
                                              unsigned short* __restrict__ out1rm) {
    __shared__ float hand[4][4][24];   // [wave][grp][4 den + 20 Xw]
    const int t = threadIdx.x;
    const int wave = t >> 6, lane = t & 63;
    const int grp = lane >> 4, l16 = lane & 15;
    const int d = blockIdx.x * 16 + wave * 4 + grp;   // exact cover

    float w1r[4][5], bias[4];
#pragma unroll
    for (int h = 0; h < 4; ++h) {
#pragma unroll
        for (int i = 0; i < 5; ++i) w1r[h][i] = W1[i * 256 + h * 64 + lane];
        bias[h] = b1[h * 64 + lane];
    }

    const int beg = row_start[d], end = row_start[d + 1];
    const float4 ad = adv[d];

    float den[4] = {0.f, 0.f, 0.f, 0.f};
    float xw[4][5];
#pragma unroll
    for (int h = 0; h < 4; ++h)
#pragma unroll
        for (int i = 0; i < 5; ++i) xw[h][i] = 0.f;

    for (int cb = beg; cb < end; cb += 16) {
        const int j = cb + l16;
        if (j < end) {
            const int s = csr_src[j];
            const float4 a = asv[s];
            float w[4];
            w[0] = __expf(lrelu(a.x + ad.x));
            w[1] = __expf(lrelu(a.y + ad.y));
            w[2] = __expf(lrelu(a.z + ad.z));
            w[3] = __expf(lrelu(a.w + ad.w));
            const float* xp = x + (size_t)s * 5;
            float xv[5];
#pragma unroll
            for (int i = 0; i < 5; ++i) xv[i] = xp[i];
#pragma unroll
            for (int h = 0; h < 4; ++h) {
                den[h] += w[h];
#pragma unroll
                for (int i = 0; i < 5; ++i) xw[h][i] += w[h] * xv[i];
            }
        }
    }

#pragma unroll
    for (int off = 1; off < 16; off <<= 1) {
#pragma unroll
        for (int h = 0; h < 4; ++h) {
            den[h] += __shfl_xor(den[h], off, 64);
#pragma unroll
            for (int i = 0; i < 5; ++i) xw[h][i] += __shfl_xor(xw[h][i], off, 64);
        }
    }

    {   // self loop
        const float4 as = asv[d];
        float w[4];
        w[0] = __expf(lrelu(as.x + ad.x));
        w[1] = __expf(lrelu(as.y + ad.y));
        w[2] = __expf(lrelu(as.z + ad.z));
        w[3] = __expf(lrelu(as.w + ad.w));
        const float* xp = x + (size_t)d * 5;
        float xv[5];
#pragma unroll
        for (int i = 0; i < 5; ++i) xv[i] = xp[i];
#pragma unroll
        for (int h = 0; h < 4; ++h) {
            den[h] += w[h];
#pragma unroll
            for (int i = 0; i < 5; ++i) xw[h][i] += w[h] * xv[i];
        }
    }

    if (l16 == 0) {
#pragma unroll
        for (int h = 0; h < 4; ++h) hand[wave][grp][h] = den[h];
#pragma unroll
        for (int h = 0; h < 4; ++h)
#pragma unroll
            for (int i = 0; i < 5; ++i) hand[wave][grp][4 + h * 5 + i] = xw[h][i];
    }
    __syncthreads();

#pragma unroll
    for (int n = 0; n < 4; ++n) {
        const int dn = blockIdx.x * 16 + wave * 4 + n;
        unsigned short* op = out1rm + (size_t)dn * 256;
#pragma unroll
        for (int h = 0; h < 4; ++h) {
            const float dh = hand[wave][n][h] + 1e-16f;
            float hh = hand[wave][n][4 + h * 5 + 0] * w1r[h][0]
                     + hand[wave][n][4 + h * 5 + 1] * w1r[h][1]
                     + hand[wave][n][4 + h * 5 + 2] * w1r[h][2]
                     + hand[wave][n][4 + h * 5 + 3] * w1r[h][3]
                     + hand[wave][n][4 + h * 5 + 4] * w1r[h][4];
            op[h * 64 + lane] = f2bf(fmaxf(hh / dh + bias[h], 0.f));
        }
    }
}

// ---------------- Layer 2: MFMA GEMM (50000x256 @ 256x64) + attention logits ----
__global__ __launch_bounds__(256) void k_gemm2(const unsigned short* __restrict__ in,
                                               const float* __restrict__ W2,
                                               const float* __restrict__ att_s2,
                                               const float* __restrict__ att_d2,
                                               unsigned short* __restrict__ h2b,
                                               float* __restrict__ a_s2,
                                               float* __restrict__ a_d2) {
    __shared__ unsigned short lW[16384];  // 32 KB: [s][g][t][c16][j]
    const int t = threadIdx.x;
    for (int idx = t; idx < 16384; idx += 256) {
        int j = idx & 7, c16 = (idx >> 3) & 15, tt = (idx >> 7) & 3,
            g = (idx >> 9) & 3, s = idx >> 11;
        int k = 32 * s + 8 * g + j, c = 16 * tt + c16;
        lW[idx] = f2bf(W2[k * 64 + c]);
    }
    __syncthreads();
    const int wave = t >> 6, lane = t & 63;
    const int g = lane >> 4, c16 = lane & 15;
    const int nb = blockIdx.x * 64 + wave * 16;
    if (nb >= N_NODES) return;

    f32x4 acc[4];
#pragma unroll
    for (int i = 0; i < 4; ++i) acc[i] = (f32x4){0.f, 0.f, 0.f, 0.f};

    const unsigned short* arow = in + (size_t)(nb + c16) * 256;  // A row = lane&15
#pragma unroll
    for (int s = 0; s < 8; ++s) {
        short8 a = *reinterpret_cast<const short8*>(arow + 32 * s + 8 * g);
#pragma unroll
        for (int tt = 0; tt < 4; ++tt) {
            short8 b = *reinterpret_cast<const short8*>(
                lW + ((((s * 4 + g) * 4 + tt) * 16 + c16) << 3));
            acc[tt] = __builtin_amdgcn_mfma_f32_16x16x32_bf16(a, b, acc[tt], 0, 0, 0);
        }
    }

    float attS[4], attD[4];
#pragma unroll
    for (int tt = 0; tt < 4; ++tt) {
        attS[tt] = att_s2[16 * tt + c16];
        attD[tt] = att_d2[16 * tt + c16];
    }
#pragma unroll
    for (int r = 0; r < 4; ++r) {
        const int node = nb + g * 4 + r;
        const bool ok = node < N_NODES;
        float vs = 0.f, vd = 0.f;
#pragma unroll
        for (int tt = 0; tt < 4; ++tt) {
            float v = acc[tt][r];
            if (ok) h2b[(size_t)node * 64 + 16 * tt + c16] = f2bf(v);
            vs += v * attS[tt];
            vd += v * attD[tt];
        }
#pragma unroll
        for (int off = 1; off < 16; off <<= 1) {
            vs += __shfl_xor(vs, off, 64);
            vd += __shfl_xor(vd, off, 64);
        }
        if (ok && c16 == 0) { a_s2[node] = vs; a_d2[node] = vd; }
    }
}

// ---------------- Layer 2 aggregation + fused pool (replicated accumulators) --
__global__ __launch_bounds__(256) void k_agg2(const unsigned short* __restrict__ h2b,
                                              const float* __restrict__ as_,
                                              const float* __restrict__ ad_,
                                              const int* __restrict__ row_start,
                                              const int* __restrict__ csr_src,
                                              const float* __restrict__ b2,
                                              const int* __restrict__ batch,
                                              float* __restrict__ sums) {
    const int wave = threadIdx.x >> 6, lane = threadIdx.x & 63;
    const int d = blockIdx.x * 4 + wave;
    if (d >= N_NODES) return;
    const int beg = row_start[d], end = row_start[d + 1];
    const float adl = ad_[d];

    float den, acc;
    {
        float w = __expf(lrelu(as_[d] + adl));
        den = (lane == 0) ? w : 0.f;
        acc = w * bf2f(h2b[(size_t)d * 64 + lane]);
    }
    for (int c = beg; c < end; c += 64) {
        int rem = end - c; if (rem > 64) rem = 64;
        int sreg = 0;
        float wr = 0.f;
        if (lane < rem) {
            sreg = csr_src[c + lane];
            wr = __expf(lrelu(as_[sreg] + adl));
            den += wr;
        }
        int e = 0;
        for (; e + 8 <= rem; e += 8) {
            int sq[8];
#pragma unroll
            for (int q = 0; q < 8; ++q) sq[q] = __shfl(sreg, e + q, 64);
            unsigned short vq[8];
#pragma unroll
            for (int q = 0; q < 8; ++q) vq[q] = h2b[(size_t)sq[q] * 64 + lane];
#pragma unroll
            for (int q = 0; q < 8; ++q) {
                acc += __shfl(wr, e + q, 64) * bf2f(vq[q]);
            }
        }
        for (; e < rem; ++e) {
            int s = __shfl(sreg, e, 64);
            acc += __shfl(wr, e, 64) * bf2f(h2b[(size_t)s * 64 + lane]);
        }
    }
#pragma unroll
    for (int off = 32; off; off >>= 1) den += __shfl_xor(den, off, 64);
    float val = fmaxf(acc / (den + 1e-16f) + b2[lane], 0.f);
    const int rep = blockIdx.x & (N_REP - 1);
    atomicAdd(&sums[(size_t)rep * (N_GRAPHS * 64) + batch[d] * 64 + lane], val);
}

// ---------------- Final: reduce replicas + mean + 64->2 linear ----------------
// 64 blocks (one per graph) x 64 lanes (lane = channel).
__global__ __launch_bounds__(64) void k_final(const float* __restrict__ sums,
                                              const int* __restrict__ batch,
                                              const float* __restrict__ linW,
                                              const float* __restrict__ linb,
                                              float* __restrict__ out) {
    const int g = blockIdx.x;
    const int lane = threadIdx.x;
    float s = 0.f;
#pragma unroll 8
    for (int r = 0; r < N_REP; ++r)
        s += sums[(size_t)r * (N_GRAPHS * 64) + g * 64 + lane];
    int beg = lower_bound_i(batch, N_NODES, g);
    int end = lower_bound_i(batch, N_NODES, g + 1);
    float val = s / fmaxf((float)(end - beg), 1.0f);
    float v0 = val * linW[lane * 2 + 0];
    float v1 = val * linW[lane * 2 + 1];
#pragma unroll
    for (int off = 32; off; off >>= 1) {
        v0 += __shfl_xor(v0, off, 64);
        v1 += __shfl_xor(v1, off, 64);
    }
    if (lane == 0) {
        out[g * 2 + 0] = v0 + linb[0];
        out[g * 2 + 1] = v1 + linb[1];
    }
}

extern "C" void kernel_launch(void* const* d_in, const int* in_sizes, int n_in,
                              void* d_out, int out_size, void* d_ws, size_t ws_size,
                              hipStream_t stream) {
    const float* x    = (const float*)d_in[0];
    const int*   ei   = (const int*)d_in[1];
    const int*   bat  = (const int*)d_in[2];
    const float* W1   = (const float*)d_in[3];
    const float* as1  = (const float*)d_in[4];
    const float* ad1  = (const float*)d_in[5];
    const float* b1   = (const float*)d_in[6];
    const float* W2   = (const float*)d_in[7];
    const float* as2  = (const float*)d_in[8];
    const float* ad2  = (const float*)d_in[9];
    const float* b2   = (const float*)d_in[10];
    const float* linW = (const float*)d_in[11];
    const float* linb = (const float*)d_in[12];
    float* out = (float*)d_out;

    const int* src = ei;
    const int* dst = ei + N_EDGES;

    char* w = (char*)d_ws;
    unsigned short* out1rm = (unsigned short*)w; w += (size_t)N_NODES * 256 * 2;
    float4* a_s1 = (float4*)w; w += (size_t)N_NODES * 16;
    float4* a_d1 = (float4*)w; w += (size_t)N_NODES * 16;
    unsigned short* h2b = (unsigned short*)w; w += (size_t)N_NODES * 64 * 2;
    float* a_s2  = (float*)w; w += (size_t)N_NODES * 4;
    float* a_d2  = (float*)w; w += (size_t)N_NODES * 4;
    float* sums  = (float*)w; w += (size_t)N_REP * N_GRAPHS * 64 * 4;
    int* counts    = (int*)w; w += (size_t)N_NODES * 4;
    int* row_start = (int*)w; w += (size_t)(N_NODES + 64) * 4;
    int* cursor    = (int*)w; w += (size_t)N_NODES * 4;
    int* csr_src   = (int*)w; w += (size_t)N_EDGES * 4;
    int* blk_sum   = (int*)w; w += 128 * 4;
    int* blk_base  = (int*)w; w += 128 * 4;

    // CSR build (multi-block scan)
    hipMemsetAsync(counts, 0, (size_t)N_NODES * 4, stream);
    hipMemsetAsync(sums, 0, (size_t)N_REP * N_GRAPHS * 64 * 4, stream);
    k_count<<<(N_EDGES + 255) / 256, 256, 0, stream>>>(dst, counts);
    k_scan1<<<SCAN_NB, SCAN_BS, 0, stream>>>(counts, cursor, blk_sum);
    k_scan2<<<1, 128, 0, stream>>>(blk_sum, blk_base, row_start);
    k_scan3<<<SCAN_NB, SCAN_BS, 0, stream>>>(cursor, blk_base, row_start, cursor);
    k_fill<<<(N_EDGES + 255) / 256, 256, 0, stream>>>(src, dst, cursor, csr_src);

    // Layer 1
    k_gemm1<<<(N_NODES + 3) / 4, 256, 0, stream>>>(x, W1, as1, ad1, a_s1, a_d1);
    k_agg1<<<N_NODES / 16, 256, 0, stream>>>(x, W1, a_s1, a_d1, row_start, csr_src, b1, out1rm);
    // Layer 2 (MFMA)
    k_gemm2<<<(N_NODES + 63) / 64, 256, 0, stream>>>(out1rm, W2, as2, ad2, h2b, a_s2, a_d2);
    k_agg2<<<(N_NODES + 3) / 4, 256, 0, stream>>>(h2b, a_s2, a_d2, row_start, csr_src, b2,
                                                  bat, sums);
    // Reduce replicas + mean + linear
    k_final<<<N_GRAPHS, 64, 0, stream>>>(sums, bat, linW, linb, out);
}

// Round 12
// 215.918 us; speedup vs baseline: 1.2330x; 1.0498x over previous
//
#include <hip/hip_runtime.h>
#include <math.h>

#define N_NODES 50000
#define N_EDGES 800000
#define N_GRAPHS 64
#define NEG_SLOPE 0.2f
#define SCAN_BS 512
#define SCAN_NB ((N_NODES + SCAN_BS - 1) / SCAN_BS)   // 98
#define N_REP 64   // pooled-sum replicas (contention breaker)

typedef __attribute__((ext_vector_type(8))) short short8;
typedef __attribute__((ext_vector_type(4))) float f32x4;

__device__ __forceinline__ float lrelu(float x) { return x > 0.f ? x : NEG_SLOPE * x; }

__device__ __forceinline__ unsigned short f2bf(float f) {
    union { float f; unsigned int u; } v; v.f = f;
    unsigned int r = (v.u + 0x7fffu + ((v.u >> 16) & 1u)) >> 16;  // RNE
    return (unsigned short)r;
}
__device__ __forceinline__ float bf2f(unsigned short b) {
    union { unsigned int u; float f; } v; v.u = ((unsigned int)b) << 16;
    return v.f;
}

__device__ __forceinline__ int lower_bound_i(const int* __restrict__ a, int n, int v) {
    int lo = 0, hi = n;
    while (lo < hi) { int m = (lo + hi) >> 1; if (a[m] < v) lo = m + 1; else hi = m; }
    return lo;
}

// ---------------- CSR build (8-edge ILP per thread) ----------------
__global__ void k_count(const int* __restrict__ dst, int* __restrict__ cnt) {
    const int base = (blockIdx.x * blockDim.x + threadIdx.x) * 8;
    if (base + 8 <= N_EDGES) {
        int4 a = *(const int4*)(dst + base);
        int4 b = *(const int4*)(dst + base + 4);
        atomicAdd(&cnt[a.x], 1); atomicAdd(&cnt[a.y], 1);
        atomicAdd(&cnt[a.z], 1); atomicAdd(&cnt[a.w], 1);
        atomicAdd(&cnt[b.x], 1); atomicAdd(&cnt[b.y], 1);
        atomicAdd(&cnt[b.z], 1); atomicAdd(&cnt[b.w], 1);
    } else {
        for (int e = base; e < N_EDGES; ++e) atomicAdd(&cnt[dst[e]], 1);
    }
}

__global__ void k_fill(const int* __restrict__ src, const int* __restrict__ dst,
                       int* __restrict__ cursor, int* __restrict__ csr_src) {
    const int base = (blockIdx.x * blockDim.x + threadIdx.x) * 8;
    if (base + 8 <= N_EDGES) {
        int4 da = *(const int4*)(dst + base);
        int4 db = *(const int4*)(dst + base + 4);
        int4 sa = *(const int4*)(src + base);
        int4 sb = *(const int4*)(src + base + 4);
        int p0 = atomicAdd(&cursor[da.x], 1);
        int p1 = atomicAdd(&cursor[da.y], 1);
        int p2 = atomicAdd(&cursor[da.z], 1);
        int p3 = atomicAdd(&cursor[da.w], 1);
        int p4 = atomicAdd(&cursor[db.x], 1);
        int p5 = atomicAdd(&cursor[db.y], 1);
        int p6 = atomicAdd(&cursor[db.z], 1);
        int p7 = atomicAdd(&cursor[db.w], 1);
        csr_src[p0] = sa.x; csr_src[p1] = sa.y;
        csr_src[p2] = sa.z; csr_src[p3] = sa.w;
        csr_src[p4] = sb.x; csr_src[p5] = sb.y;
        csr_src[p6] = sb.z; csr_src[p7] = sb.w;
    } else {
        for (int e = base; e < N_EDGES; ++e) {
            int p = atomicAdd(&cursor[dst[e]], 1);
            csr_src[p] = src[e];
        }
    }
}

__global__ __launch_bounds__(SCAN_BS) void k_scan1(const int* __restrict__ cnt,
                                                   int* __restrict__ local_pref,
                                                   int* __restrict__ blk_sum) {
    const int t = threadIdx.x;
    const int gid = blockIdx.x * SCAN_BS + t;
    const int lane = t & 63, w = t >> 6;
    int v = (gid < N_NODES) ? cnt[gid] : 0;
    int x = v;
#pragma unroll
    for (int off = 1; off < 64; off <<= 1) {
        int y = __shfl_up(x, off, 64);
        if (lane >= off) x += y;
    }
    __shared__ int wsum[SCAN_BS / 64];
    __shared__ int wpre[SCAN_BS / 64];
    if (lane == 63) wsum[w] = x;
    __syncthreads();
    if (t == 0) {
        int run = 0;
#pragma unroll
        for (int i = 0; i < SCAN_BS / 64; ++i) { wpre[i] = run; run += wsum[i]; }
    }
    __syncthreads();
    int excl = x - v + wpre[w];
    if (gid < N_NODES) local_pref[gid] = excl;
    if (t == SCAN_BS - 1) blk_sum[blockIdx.x] = excl + v;
}

__global__ __launch_bounds__(128) void k_scan2(const int* __restrict__ blk_sum,
                                               int* __restrict__ blk_base,
                                               int* __restrict__ row_start) {
    const int t = threadIdx.x;
    const int lane = t & 63;
    int v = (t < SCAN_NB) ? blk_sum[t] : 0;
    int x = v;
#pragma unroll
    for (int off = 1; off < 64; off <<= 1) {
        int y = __shfl_up(x, off, 64);
        if (lane >= off) x += y;
    }
    __shared__ int wsum0;
    if (t == 63) wsum0 = x;
    __syncthreads();
    int excl = x - v + ((t >= 64) ? wsum0 : 0);
    if (t < SCAN_NB) blk_base[t] = excl;
    if (t == 127) row_start[N_NODES] = excl + v;  // grand total
}

__global__ __launch_bounds__(SCAN_BS) void k_scan3(const int* __restrict__ local_pref,
                                                   const int* __restrict__ blk_base,
                                                   int* __restrict__ row_start,
                                                   int* __restrict__ cursor) {
    const int gid = blockIdx.x * SCAN_BS + threadIdx.x;
    if (gid < N_NODES) {
        int r = local_pref[gid] + blk_base[blockIdx.x];
        row_start[gid] = r;
        cursor[gid] = r;
    }
}

// ---------------- Layer 1 logits: a_s/a_d per node (h1 NOT materialized) -----
__global__ __launch_bounds__(256) void k_gemm1(const float* __restrict__ x,
                                               const float* __restrict__ W1,
                                               const float* __restrict__ att_s,
                                               const float* __restrict__ att_d,
                                               float4* __restrict__ a_s,
                                               float4* __restrict__ a_d) {
    __shared__ float Ws[5 * 256];
    const int t = threadIdx.x;
    for (int i = t; i < 5 * 256; i += 256) Ws[i] = W1[i];
    __syncthreads();
    const int wave = t >> 6, lane = t & 63;
    const int n = blockIdx.x * 4 + wave;
    if (n >= N_NODES) return;
    float x0 = x[n * 5 + 0], x1 = x[n * 5 + 1], x2 = x[n * 5 + 2],
          x3 = x[n * 5 + 3], x4 = x[n * 5 + 4];
    float vs[4], vd[4];
#pragma unroll
    for (int hd = 0; hd < 4; ++hd) {
        const int c = hd * 64 + lane;
        float h = x0 * Ws[c] + x1 * Ws[256 + c] + x2 * Ws[512 + c] +
                  x3 * Ws[768 + c] + x4 * Ws[1024 + c];
        vs[hd] = h * att_s[c];
        vd[hd] = h * att_d[c];
    }
#pragma unroll
    for (int off = 32; off; off >>= 1) {
#pragma unroll
        for (int hd = 0; hd < 4; ++hd) {
            vs[hd] += __shfl_xor(vs[hd], off, 64);
            vd[hd] += __shfl_xor(vd[hd], off, 64);
        }
    }
    if (lane == 0) {
        a_s[n] = make_float4(vs[0], vs[1], vs[2], vs[3]);
        a_d[n] = make_float4(vd[0], vd[1], vd[2], vd[3]);
    }
}

// ---------------- Layer 1 aggregation: SUM-SWAPPED ----------------
__global__ __launch_bounds__(256) void k_agg1(const float* __restrict__ x,
                                              const float* __restrict__ W1,
                                              const float4* __restrict__ asv,
                                              const float4* __restrict__ adv,
                                              const int* __restrict__ row_start,
                                              const int* __restrict__ csr_src,
                                              const float* __restrict__ b1,
                                              unsigned short* __restrict__ out1rm) {
    __shared__ float hand[4][4][24];   // [wave][grp][4 den + 20 Xw]
    const int t = threadIdx.x;
    const int wave = t >> 6, lane = t & 63;
    const int grp = lane >> 4, l16 = lane & 15;
    const int d = blockIdx.x * 16 + wave * 4 + grp;   // exact cover

    float w1r[4][5], bias[4];
#pragma unroll
    for (int h = 0; h < 4; ++h) {
#pragma unroll
        for (int i = 0; i < 5; ++i) w1r[h][i] = W1[i * 256 + h * 64 + lane];
        bias[h] = b1[h * 64 + lane];
    }

    const int beg = row_start[d], end = row_start[d + 1];
    const float4 ad = adv[d];

    float den[4] = {0.f, 0.f, 0.f, 0.f};
    float xw[4][5];
#pragma unroll
    for (int h = 0; h < 4; ++h)
#pragma unroll
        for (int i = 0; i < 5; ++i) xw[h][i] = 0.f;

    for (int cb = beg; cb < end; cb += 16) {
        const int j = cb + l16;
        if (j < end) {
            const int s = csr_src[j];
            const float4 a = asv[s];
            float w[4];
            w[0] = __expf(lrelu(a.x + ad.x));
            w[1] = __expf(lrelu(a.y + ad.y));
            w[2] = __expf(lrelu(a.z + ad.z));
            w[3] = __expf(lrelu(a.w + ad.w));
            const float* xp = x + (size_t)s * 5;
            float xv[5];
#pragma unroll
            for (int i = 0; i < 5; ++i) xv[i] = xp[i];
#pragma unroll
            for (int h = 0; h < 4; ++h) {
                den[h] += w[h];
#pragma unroll
                for (int i = 0; i < 5; ++i) xw[h][i] += w[h] * xv[i];
            }
        }
    }

#pragma unroll
    for (int off = 1; off < 16; off <<= 1) {
#pragma unroll
        for (int h = 0; h < 4; ++h) {
            den[h] += __shfl_xor(den[h], off, 64);
#pragma unroll
            for (int i = 0; i < 5; ++i) xw[h][i] += __shfl_xor(xw[h][i], off, 64);
        }
    }

    {   // self loop
        const float4 as = asv[d];
        float w[4];
        w[0] = __expf(lrelu(as.x + ad.x));
        w[1] = __expf(lrelu(as.y + ad.y));
        w[2] = __expf(lrelu(as.z + ad.z));
        w[3] = __expf(lrelu(as.w + ad.w));
        const float* xp = x + (size_t)d * 5;
        float xv[5];
#pragma unroll
        for (int i = 0; i < 5; ++i) xv[i] = xp[i];
#pragma unroll
        for (int h = 0; h < 4; ++h) {
            den[h] += w[h];
#pragma unroll
            for (int i = 0; i < 5; ++i) xw[h][i] += w[h] * xv[i];
        }
    }

    if (l16 == 0) {
#pragma unroll
        for (int h = 0; h < 4; ++h) hand[wave][grp][h] = den[h];
#pragma unroll
        for (int h = 0; h < 4; ++h)
#pragma unroll
            for (int i = 0; i < 5; ++i) hand[wave][grp][4 + h * 5 + i] = xw[h][i];
    }
    __syncthreads();

#pragma unroll
    for (int n = 0; n < 4; ++n) {
        const int dn = blockIdx.x * 16 + wave * 4 + n;
        unsigned short* op = out1rm + (size_t)dn * 256;
#pragma unroll
        for (int h = 0; h < 4; ++h) {
            const float dh = hand[wave][n][h] + 1e-16f;
            float hh = hand[wave][n][4 + h * 5 + 0] * w1r[h][0]
                     + hand[wave][n][4 + h * 5 + 1] * w1r[h][1]
                     + hand[wave][n][4 + h * 5 + 2] * w1r[h][2]
                     + hand[wave][n][4 + h * 5 + 3] * w1r[h][3]
                     + hand[wave][n][4 + h * 5 + 4] * w1r[h][4];
            op[h * 64 + lane] = f2bf(fmaxf(hh / dh + bias[h], 0.f));
        }
    }
}

// ---------------- Layer 2: MFMA GEMM (50000x256 @ 256x64) + attention logits ----
__global__ __launch_bounds__(256) void k_gemm2(const unsigned short* __restrict__ in,
                                               const float* __restrict__ W2,
                                               const float* __restrict__ att_s2,
                                               const float* __restrict__ att_d2,
                                               unsigned short* __restrict__ h2b,
                                               float* __restrict__ a_s2,
                                               float* __restrict__ a_d2) {
    __shared__ unsigned short lW[16384];  // 32 KB: [s][g][t][c16][j]
    const int t = threadIdx.x;
    for (int idx = t; idx < 16384; idx += 256) {
        int j = idx & 7, c16 = (idx >> 3) & 15, tt = (idx >> 7) & 3,
            g = (idx >> 9) & 3, s = idx >> 11;
        int k = 32 * s + 8 * g + j, c = 16 * tt + c16;
        lW[idx] = f2bf(W2[k * 64 + c]);
    }
    __syncthreads();
    const int wave = t >> 6, lane = t & 63;
    const int g = lane >> 4, c16 = lane & 15;
    const int nb = blockIdx.x * 64 + wave * 16;
    if (nb >= N_NODES) return;

    f32x4 acc[4];
#pragma unroll
    for (int i = 0; i < 4; ++i) acc[i] = (f32x4){0.f, 0.f, 0.f, 0.f};

    const unsigned short* arow = in + (size_t)(nb + c16) * 256;  // A row = lane&15
#pragma unroll
    for (int s = 0; s < 8; ++s) {
        short8 a = *reinterpret_cast<const short8*>(arow + 32 * s + 8 * g);
#pragma unroll
        for (int tt = 0; tt < 4; ++tt) {
            short8 b = *reinterpret_cast<const short8*>(
                lW + ((((s * 4 + g) * 4 + tt) * 16 + c16) << 3));
            acc[tt] = __builtin_amdgcn_mfma_f32_16x16x32_bf16(a, b, acc[tt], 0, 0, 0);
        }
    }

    float attS[4], attD[4];
#pragma unroll
    for (int tt = 0; tt < 4; ++tt) {
        attS[tt] = att_s2[16 * tt + c16];
        attD[tt] = att_d2[16 * tt + c16];
    }
#pragma unroll
    for (int r = 0; r < 4; ++r) {
        const int node = nb + g * 4 + r;
        const bool ok = node < N_NODES;
        float vs = 0.f, vd = 0.f;
#pragma unroll
        for (int tt = 0; tt < 4; ++tt) {
            float v = acc[tt][r];
            if (ok) h2b[(size_t)node * 64 + 16 * tt + c16] = f2bf(v);
            vs += v * attS[tt];
            vd += v * attD[tt];
        }
#pragma unroll
        for (int off = 1; off < 16; off <<= 1) {
            vs += __shfl_xor(vs, off, 64);
            vd += __shfl_xor(vd, off, 64);
        }
        if (ok && c16 == 0) { a_s2[node] = vs; a_d2[node] = vd; }
    }
}

// ---------------- Layer 2 aggregation + fused pool (replicated accumulators) --
__global__ __launch_bounds__(256) void k_agg2(const unsigned short* __restrict__ h2b,
                                              const float* __restrict__ as_,
                                              const float* __restrict__ ad_,
                                              const int* __restrict__ row_start,
                                              const int* __restrict__ csr_src,
                                              const float* __restrict__ b2,
                                              const int* __restrict__ batch,
                                              float* __restrict__ sums) {
    const int wave = threadIdx.x >> 6, lane = threadIdx.x & 63;
    const int d = blockIdx.x * 4 + wave;
    if (d >= N_NODES) return;
    const int beg = row_start[d], end = row_start[d + 1];
    const float adl = ad_[d];

    float den, acc;
    {
        float w = __expf(lrelu(as_[d] + adl));
        den = (lane == 0) ? w : 0.f;
        acc = w * bf2f(h2b[(size_t)d * 64 + lane]);
    }
    for (int c = beg; c < end; c += 64) {
        int rem = end - c; if (rem > 64) rem = 64;
        int sreg = 0;
        float wr = 0.f;
        if (lane < rem) {
            sreg = csr_src[c + lane];
            wr = __expf(lrelu(as_[sreg] + adl));
            den += wr;
        }
        int e = 0;
        for (; e + 8 <= rem; e += 8) {
            int sq[8];
#pragma unroll
            for (int q = 0; q < 8; ++q) sq[q] = __shfl(sreg, e + q, 64);
            unsigned short vq[8];
#pragma unroll
            for (int q = 0; q < 8; ++q) vq[q] = h2b[(size_t)sq[q] * 64 + lane];
#pragma unroll
            for (int q = 0; q < 8; ++q) {
                acc += __shfl(wr, e + q, 64) * bf2f(vq[q]);
            }
        }
        for (; e < rem; ++e) {
            int s = __shfl(sreg, e, 64);
            acc += __shfl(wr, e, 64) * bf2f(h2b[(size_t)s * 64 + lane]);
        }
    }
#pragma unroll
    for (int off = 32; off; off >>= 1) den += __shfl_xor(den, off, 64);
    float val = fmaxf(acc / (den + 1e-16f) + b2[lane], 0.f);
    const int rep = blockIdx.x & (N_REP - 1);
    atomicAdd(&sums[(size_t)rep * (N_GRAPHS * 64) + batch[d] * 64 + lane], val);
}

// ---------------- Final: reduce replicas + mean + 64->2 linear ----------------
__global__ __launch_bounds__(64) void k_final(const float* __restrict__ sums,
                                              const int* __restrict__ batch,
                                              const float* __restrict__ linW,
                                              const float* __restrict__ linb,
                                              float* __restrict__ out) {
    const int g = blockIdx.x;
    const int lane = threadIdx.x;
    float s = 0.f;
#pragma unroll 8
    for (int r = 0; r < N_REP; ++r)
        s += sums[(size_t)r * (N_GRAPHS * 64) + g * 64 + lane];
    int beg = lower_bound_i(batch, N_NODES, g);
    int end = lower_bound_i(batch, N_NODES, g + 1);
    float val = s / fmaxf((float)(end - beg), 1.0f);
    float v0 = val * linW[lane * 2 + 0];
    float v1 = val * linW[lane * 2 + 1];
#pragma unroll
    for (int off = 32; off; off >>= 1) {
        v0 += __shfl_xor(v0, off, 64);
        v1 += __shfl_xor(v1, off, 64);
    }
    if (lane == 0) {
        out[g * 2 + 0] = v0 + linb[0];
        out[g * 2 + 1] = v1 + linb[1];
    }
}

extern "C" void kernel_launch(void* const* d_in, const int* in_sizes, int n_in,
                              void* d_out, int out_size, void* d_ws, size_t ws_size,
                              hipStream_t stream) {
    const float* x    = (const float*)d_in[0];
    const int*   ei   = (const int*)d_in[1];
    const int*   bat  = (const int*)d_in[2];
    const float* W1   = (const float*)d_in[3];
    const float* as1  = (const float*)d_in[4];
    const float* ad1  = (const float*)d_in[5];
    const float* b1   = (const float*)d_in[6];
    const float* W2   = (const float*)d_in[7];
    const float* as2  = (const float*)d_in[8];
    const float* ad2  = (const float*)d_in[9];
    const float* b2   = (const float*)d_in[10];
    const float* linW = (const float*)d_in[11];
    const float* linb = (const float*)d_in[12];
    float* out = (float*)d_out;

    const int* src = ei;
    const int* dst = ei + N_EDGES;

    char* w = (char*)d_ws;
    unsigned short* out1rm = (unsigned short*)w; w += (size_t)N_NODES * 256 * 2;
    float4* a_s1 = (float4*)w; w += (size_t)N_NODES * 16;
    float4* a_d1 = (float4*)w; w += (size_t)N_NODES * 16;
    unsigned short* h2b = (unsigned short*)w; w += (size_t)N_NODES * 64 * 2;
    float* a_s2  = (float*)w; w += (size_t)N_NODES * 4;
    float* a_d2  = (float*)w; w += (size_t)N_NODES * 4;
    // counts + sums adjacent: ONE memset covers both
    int* counts  = (int*)w;   w += (size_t)N_NODES * 4;
    float* sums  = (float*)w; w += (size_t)N_REP * N_GRAPHS * 64 * 4;
    int* row_start = (int*)w; w += (size_t)(N_NODES + 64) * 4;
    int* cursor    = (int*)w; w += (size_t)N_NODES * 4;
    int* csr_src   = (int*)w; w += (size_t)N_EDGES * 4;
    int* blk_sum   = (int*)w; w += 128 * 4;
    int* blk_base  = (int*)w; w += 128 * 4;

    // CSR build (multi-block scan)
    hipMemsetAsync(counts, 0, (size_t)N_NODES * 4 + (size_t)N_REP * N_GRAPHS * 64 * 4, stream);
    k_count<<<(N_EDGES / 8 + 255) / 256, 256, 0, stream>>>(dst, counts);
    k_scan1<<<SCAN_NB, SCAN_BS, 0, stream>>>(counts, cursor, blk_sum);
    k_scan2<<<1, 128, 0, stream>>>(blk_sum, blk_base, row_start);
    k_scan3<<<SCAN_NB, SCAN_BS, 0, stream>>>(cursor, blk_base, row_start, cursor);
    k_fill<<<(N_EDGES / 8 + 255) / 256, 256, 0, stream>>>(src, dst, cursor, csr_src);

    // Layer 1
    k_gemm1<<<(N_NODES + 3) / 4, 256, 0, stream>>>(x, W1, as1, ad1, a_s1, a_d1);
    k_agg1<<<N_NODES / 16, 256, 0, stream>>>(x, W1, a_s1, a_d1, row_start, csr_src, b1, out1rm);
    // Layer 2 (MFMA)
    k_gemm2<<<(N_NODES + 63) / 64, 256, 0, stream>>>(out1rm, W2, as2, ad2, h2b, a_s2, a_d2);
    k_agg2<<<(N_NODES + 3) / 4, 256, 0, stream>>>(h2b, a_s2, a_d2, row_start, csr_src, b2,
                                                  bat, sums);
    // Reduce replicas + mean + linear
    k_final<<<N_GRAPHS, 64, 0, stream>>>(sums, bat, linW, linb, out);
}